// Round 1
// baseline (1193.059 us; speedup 1.0000x reference)
//
#include <hip/hip_runtime.h>
#include <hip/hip_bf16.h>

// RetAttention: B=2 H=16 S=2048 D=128, fp32 in/out.
// o = ((q k^T) * mask / clip(sum|.|, 1, inf)) @ v
// Strategy: streaming (no-softmax) flash-style kernel, bf16 MFMA,
// transposed S' = K Q^T so the QK output frag feeds PV directly (no shuffles),
// both batches per block so the 268 MB mask is read exactly once.

#define NB 2
#define NH 16
#define NS 2048
#define ND 128

typedef __bf16 bf16x8 __attribute__((ext_vector_type(8)));
typedef __bf16 bf16x4 __attribute__((ext_vector_type(4)));
typedef short s16x4 __attribute__((ext_vector_type(4)));
typedef unsigned short u16x8 __attribute__((ext_vector_type(8)));
typedef float f32x4 __attribute__((ext_vector_type(4)));

static __device__ __forceinline__ unsigned short f2bf_bits(float f) {
  __hip_bfloat16 h = __float2bfloat16(f);
  return __builtin_bit_cast(unsigned short, h);
}

// ---- prepro 1: k (fp32) -> kb (bf16), elementwise ----
__global__ void cvt_k_kernel(const float* __restrict__ in,
                             unsigned short* __restrict__ outp) {
  const size_t i = ((size_t)blockIdx.x * 256 + threadIdx.x) * 8;
  const float4 a = *(const float4*)(in + i);
  const float4 b = *(const float4*)(in + i + 4);
  u16x8 u;
  u[0] = f2bf_bits(a.x); u[1] = f2bf_bits(a.y);
  u[2] = f2bf_bits(a.z); u[3] = f2bf_bits(a.w);
  u[4] = f2bf_bits(b.x); u[5] = f2bf_bits(b.y);
  u[6] = f2bf_bits(b.z); u[7] = f2bf_bits(b.w);
  *(u16x8*)(outp + i) = u;
}

// ---- prepro 2: v [BH][S][D] fp32 -> vt [BH][D][S] bf16 (tiled transpose) ----
__global__ void vtrans_kernel(const float* __restrict__ v,
                              unsigned short* __restrict__ vt) {
  __shared__ unsigned short tile[32][33];
  const int bh = blockIdx.y;        // 0..31
  const int tt = blockIdx.x >> 2;   // t tile, 0..63
  const int td = blockIdx.x & 3;    // d tile, 0..3
  const int l = threadIdx.x;        // 0..63
  const int rrow = l >> 3;          // 0..7
  const int c0 = (l & 7) * 4;
  const float* vp = v + ((size_t)bh * NS + (size_t)tt * 32) * ND + td * 32;
#pragma unroll
  for (int rr = 0; rr < 4; ++rr) {
    const int r = rr * 8 + rrow;
    const float4 x = *(const float4*)(vp + (size_t)r * ND + c0);
    tile[r][c0 + 0] = f2bf_bits(x.x);
    tile[r][c0 + 1] = f2bf_bits(x.y);
    tile[r][c0 + 2] = f2bf_bits(x.z);
    tile[r][c0 + 3] = f2bf_bits(x.w);
  }
  __syncthreads();
  unsigned short* wp = vt + ((size_t)bh * ND + (size_t)td * 32) * NS + (size_t)tt * 32;
#pragma unroll
  for (int rr = 0; rr < 4; ++rr) {
    const int dr = rr * 8 + rrow;   // local d row
    ushort4 o;
    o.x = tile[c0 + 0][dr];
    o.y = tile[c0 + 1][dr];
    o.z = tile[c0 + 2][dr];
    o.w = tile[c0 + 3][dr];
    *(ushort4*)(wp + (size_t)dr * NS + c0) = o;
  }
}

// ---- main kernel ----
// grid: (S/64, H). block: 256 threads = 4 waves, wave owns 16 q-rows, both batches.
// Per 16-t step:
//   S'[t][r] = sum_d K[t][d] Q[r][d]    (4x mfma 16x16x32 bf16, A=K, B=Q)
//   s *= mask[r][t] (float4 per lane); racc += |s|
//   O^T[d][r] += V^T[d][t] P^T[t][r]    (8x mfma 16x16x16 bf16_1k, A=V^T, B=P)
// Final: reduce racc over lane groups (shfl_xor 16,32), O = O_acc / max(racc,1).
__global__ __launch_bounds__(256, 2) void ret_attn_kernel(
    const float* __restrict__ q, const unsigned short* __restrict__ kb,
    const float* __restrict__ mask, const unsigned short* __restrict__ vt,
    float* __restrict__ out) {
  const int h = blockIdx.y;
  const int qt = blockIdx.x;
  const int tid = threadIdx.x;
  const int wave = tid >> 6;
  const int lane = tid & 63;
  const int g = lane >> 4;
  const int li = lane & 15;
  const int r = qt * 64 + wave * 16 + li;  // q row in S

  // Q fragments (B-operand of QK mfma: col = li -> r, k over d), hoisted.
  bf16x8 qf[NB][4];
#pragma unroll
  for (int b = 0; b < NB; ++b) {
    const float* qp = q + (((size_t)b * NH + h) * NS + r) * ND;
#pragma unroll
    for (int c = 0; c < 4; ++c) {
      const float4 x0 = *(const float4*)(qp + c * 32 + g * 8);
      const float4 x1 = *(const float4*)(qp + c * 32 + g * 8 + 4);
      bf16x8 f;
      f[0] = (__bf16)x0.x; f[1] = (__bf16)x0.y;
      f[2] = (__bf16)x0.z; f[3] = (__bf16)x0.w;
      f[4] = (__bf16)x1.x; f[5] = (__bf16)x1.y;
      f[6] = (__bf16)x1.z; f[7] = (__bf16)x1.w;
      qf[b][c] = f;
    }
  }

  f32x4 of[NB][8];
#pragma unroll
  for (int b = 0; b < NB; ++b)
#pragma unroll
    for (int dc = 0; dc < 8; ++dc) of[b][dc] = (f32x4){0.f, 0.f, 0.f, 0.f};
  float racc[NB] = {0.f, 0.f};

  const float* mrow = mask + ((size_t)h * NS + r) * NS;

  for (int t0 = 0; t0 < NS; t0 += 16) {
    // mask[h][r][t0+4g .. +3], one float4 per lane; shared by both batches.
    const float4 m4 = *(const float4*)(mrow + t0 + g * 4);
#pragma unroll
    for (int b = 0; b < NB; ++b) {
      const unsigned short* kp =
          kb + (((size_t)b * NH + h) * NS + (size_t)(t0 + li)) * ND + g * 8;
      f32x4 s = {0.f, 0.f, 0.f, 0.f};
#pragma unroll
      for (int c = 0; c < 4; ++c) {
        const bf16x8 kf = __builtin_bit_cast(bf16x8, *(const u16x8*)(kp + c * 32));
        s = __builtin_amdgcn_mfma_f32_16x16x32_bf16(kf, qf[b][c], s, 0, 0, 0);
      }
      // s[i] = S'[t0+4g+i][r]
      s[0] *= m4.x; s[1] *= m4.y; s[2] *= m4.z; s[3] *= m4.w;
      racc[b] += __builtin_fabsf(s[0]) + __builtin_fabsf(s[1]) +
                 __builtin_fabsf(s[2]) + __builtin_fabsf(s[3]);
      bf16x4 pb;
      pb[0] = (__bf16)s[0]; pb[1] = (__bf16)s[1];
      pb[2] = (__bf16)s[2]; pb[3] = (__bf16)s[3];
      const s16x4 pfrag = __builtin_bit_cast(s16x4, pb);
      const unsigned short* vp = vt + ((size_t)b * NH + h) * (size_t)ND * NS +
                                 (size_t)li * NS + t0 + g * 4;
#pragma unroll
      for (int dc = 0; dc < 8; ++dc) {
        const s16x4 vf = *(const s16x4*)(vp + (size_t)dc * 16 * NS);
        of[b][dc] =
            __builtin_amdgcn_mfma_f32_16x16x16bf16_1k(vf, pfrag, of[b][dc], 0, 0, 0);
      }
    }
  }

#pragma unroll
  for (int b = 0; b < NB; ++b) {
    float rt = racc[b];
    rt += __shfl_xor(rt, 16, 64);
    rt += __shfl_xor(rt, 32, 64);
    const float inv = 1.0f / fmaxf(rt, 1.0f);
    float* op = out + (((size_t)b * NH + h) * NS + r) * ND + g * 4;
#pragma unroll
    for (int dc = 0; dc < 8; ++dc) {
      float4 o4;
      o4.x = of[b][dc][0] * inv;
      o4.y = of[b][dc][1] * inv;
      o4.z = of[b][dc][2] * inv;
      o4.w = of[b][dc][3] * inv;
      *(float4*)(op + dc * 16) = o4;
    }
  }
}

extern "C" void kernel_launch(void* const* d_in, const int* in_sizes, int n_in,
                              void* d_out, int out_size, void* d_ws, size_t ws_size,
                              hipStream_t stream) {
  const float* q = (const float*)d_in[0];
  const float* k = (const float*)d_in[1];
  const float* v = (const float*)d_in[2];
  const float* mask = (const float*)d_in[3];
  float* out = (float*)d_out;

  const size_t n_qkv = (size_t)NB * NH * NS * ND;  // 8388608
  unsigned short* kb = (unsigned short*)d_ws;       // bf16 K, 16.8 MB
  unsigned short* vt = kb + n_qkv;                  // bf16 V^T [BH][D][S], 16.8 MB

  cvt_k_kernel<<<(int)(n_qkv / 8 / 256), 256, 0, stream>>>(k, kb);
  vtrans_kernel<<<dim3(256, NB * NH), 64, 0, stream>>>(v, vt);
  ret_attn_kernel<<<dim3(NS / 64, NH), 256, 0, stream>>>(q, kb, mask, vt, out);
}

// Round 2
// 633.799 us; speedup vs baseline: 1.8824x; 1.8824x over previous
//
#include <hip/hip_runtime.h>
#include <hip/hip_bf16.h>

// RetAttention: B=2 H=16 S=2048 D=128, fp32 in/out.
// o = ((q k^T) * mask / clip(sum|.|, 1, inf)) @ v
// v2: fragment-ordered packed K/V in workspace -> all main-loop loads are
// 16B/lane fully-coalesced; register prefetch pipeline (K/V depth 1, mask
// depth 2); no LDS/barriers in main loop; XCD-chunked block swizzle.

#define NB 2
#define NH 16
#define NS 2048
#define ND 128
#define STEPS 128  // NS / 16

typedef __bf16 bf16x8 __attribute__((ext_vector_type(8)));
typedef __bf16 bf16x4 __attribute__((ext_vector_type(4)));
typedef short s16x4 __attribute__((ext_vector_type(4)));
typedef short s16x8 __attribute__((ext_vector_type(8)));
typedef unsigned short u16x8 __attribute__((ext_vector_type(8)));
typedef float f32x4 __attribute__((ext_vector_type(4)));

static __device__ __forceinline__ unsigned short f2bf_bits(float f) {
  __hip_bfloat16 h = __float2bfloat16(f);
  return __builtin_bit_cast(unsigned short, h);
}

// ---- K pack: frag-ordered [bh][s][c][64 lanes]x16B ----
// frag(c, p=li*4+g)[j] = bf16(K[bh][s*16+li][c*32+g*8+j]), j=0..7
__global__ void kpack_kernel(const float* __restrict__ k,
                             unsigned short* __restrict__ kp) {
  __shared__ float tile[16 * 132];
  const int s = blockIdx.x, bh = blockIdx.y, l = threadIdx.x;
  const float* src = k + ((size_t)bh * NS + (size_t)s * 16) * ND;
#pragma unroll
  for (int j = 0; j < 8; ++j) {
    const int idx = j * 64 + l, row = idx >> 5, c4 = idx & 31;
    const float4 x = *(const float4*)(src + row * ND + c4 * 4);
    *(float4*)(tile + row * 132 + c4 * 4) = x;
  }
  __syncthreads();
  const int li = l >> 2, g = l & 3;
  unsigned short* dst = kp + ((size_t)bh * STEPS + s) * 2048 + l * 8;
#pragma unroll
  for (int c = 0; c < 4; ++c) {
    const float* tp = tile + li * 132 + c * 32 + g * 8;
    u16x8 f;
#pragma unroll
    for (int j = 0; j < 8; ++j) f[j] = f2bf_bits(tp[j]);
    *(u16x8*)(dst + c * 512) = f;
  }
}

// ---- V pack: frag-ordered [bh][s][dcp][64 lanes]x16B ----
// frag(dcp, p)[j]   = bf16(V[bh][s*16+g*4+j][dcp*16+li])      (dc = dcp)
// frag(dcp, p)[j+4] = bf16(V[bh][s*16+g*4+j][dcp*16+64+li])   (dc = dcp+4)
__global__ void vpack_kernel(const float* __restrict__ v,
                             unsigned short* __restrict__ vp) {
  __shared__ float tile[16 * 132];
  const int s = blockIdx.x, bh = blockIdx.y, l = threadIdx.x;
  const float* src = v + ((size_t)bh * NS + (size_t)s * 16) * ND;
#pragma unroll
  for (int j = 0; j < 8; ++j) {
    const int idx = j * 64 + l, row = idx >> 5, c4 = idx & 31;
    const float4 x = *(const float4*)(src + row * ND + c4 * 4);
    *(float4*)(tile + row * 132 + c4 * 4) = x;
  }
  __syncthreads();
  const int li = l >> 2, g = l & 3;
  unsigned short* dst = vp + ((size_t)bh * STEPS + s) * 2048 + l * 8;
#pragma unroll
  for (int dcp = 0; dcp < 4; ++dcp) {
    u16x8 f;
#pragma unroll
    for (int j = 0; j < 4; ++j) {
      f[j] = f2bf_bits(tile[(g * 4 + j) * 132 + dcp * 16 + li]);
      f[j + 4] = f2bf_bits(tile[(g * 4 + j) * 132 + dcp * 16 + 64 + li]);
    }
    *(u16x8*)(dst + dcp * 512) = f;
  }
}

// ---- main kernel ----
__global__ __launch_bounds__(256, 2) void ret_attn_kernel(
    const float* __restrict__ q, const unsigned short* __restrict__ kpk,
    const float* __restrict__ mask, const unsigned short* __restrict__ vpk,
    float* __restrict__ out) {
  // XCD-chunked swizzle: 512 blocks, xcd = bid&7 gets contiguous 64-block
  // chunk -> 2 heads per XCD, K/V L2-resident.
  const int bid = blockIdx.x;
  const int oo = (bid & 7) * 64 + (bid >> 3);
  const int h = oo >> 5, qt = oo & 31;
  const int tid = threadIdx.x;
  const int wave = tid >> 6, lane = tid & 63;
  const int g = lane >> 4, li = lane & 15;
  const int p = li * 4 + g;
  const int r = qt * 64 + wave * 16 + li;

  // Q fragments (B-operand of QK mfma), hoisted.
  bf16x8 qf[NB][4];
#pragma unroll
  for (int b = 0; b < NB; ++b) {
    const float* qp = q + (((size_t)b * NH + h) * NS + r) * ND;
#pragma unroll
    for (int c = 0; c < 4; ++c) {
      const float4 x0 = *(const float4*)(qp + c * 32 + g * 8);
      const float4 x1 = *(const float4*)(qp + c * 32 + g * 8 + 4);
      bf16x8 f;
      f[0] = (__bf16)x0.x; f[1] = (__bf16)x0.y;
      f[2] = (__bf16)x0.z; f[3] = (__bf16)x0.w;
      f[4] = (__bf16)x1.x; f[5] = (__bf16)x1.y;
      f[6] = (__bf16)x1.z; f[7] = (__bf16)x1.w;
      qf[b][c] = f;
    }
  }

  f32x4 of[NB][8];
#pragma unroll
  for (int b = 0; b < NB; ++b)
#pragma unroll
    for (int dc = 0; dc < 8; ++dc) of[b][dc] = (f32x4){0.f, 0.f, 0.f, 0.f};
  float racc[NB] = {0.f, 0.f};

  const unsigned short* kpb[NB];
  const unsigned short* vpb[NB];
#pragma unroll
  for (int b = 0; b < NB; ++b) {
    const size_t base = ((size_t)(b * NH + h) * STEPS) * 2048 + (size_t)p * 8;
    kpb[b] = kpk + base;
    vpb[b] = vpk + base;
  }
  const float* mrow = mask + ((size_t)h * NS + r) * NS + g * 4;

  // prologue: load step-0 frags + mask steps 0,1
  u16x8 kf[NB][4], vf[NB][4];
#pragma unroll
  for (int b = 0; b < NB; ++b)
#pragma unroll
    for (int c = 0; c < 4; ++c) {
      kf[b][c] = *(const u16x8*)(kpb[b] + c * 512);
      vf[b][c] = *(const u16x8*)(vpb[b] + c * 512);
    }
  float4 mc = *(const float4*)(mrow);
  float4 mn = *(const float4*)(mrow + 16);
  const float* mpt = mrow + 32;
#pragma unroll
  for (int b = 0; b < NB; ++b) { kpb[b] += 2048; vpb[b] += 2048; }

  for (int s = 0; s < STEPS; ++s) {
    // QK: S'[t][r] over 16 t-values
    f32x4 sv[NB];
#pragma unroll
    for (int b = 0; b < NB; ++b) {
      f32x4 acc = {0.f, 0.f, 0.f, 0.f};
#pragma unroll
      for (int c = 0; c < 4; ++c)
        acc = __builtin_amdgcn_mfma_f32_16x16x32_bf16(
            __builtin_bit_cast(bf16x8, kf[b][c]), qf[b][c], acc, 0, 0, 0);
      sv[b] = acc;
    }
    // prefetch next-step K frags (kf regs just consumed)
    u16x8 kn[NB][4];
#pragma unroll
    for (int b = 0; b < NB; ++b)
#pragma unroll
      for (int c = 0; c < 4; ++c)
        kn[b][c] = *(const u16x8*)(kpb[b] + c * 512);

    // mask * S', abs-sum, cvt to bf16 P-frag
    s16x4 pfrag[NB];
#pragma unroll
    for (int b = 0; b < NB; ++b) {
      f32x4 sp = sv[b];
      sp[0] *= mc.x; sp[1] *= mc.y; sp[2] *= mc.z; sp[3] *= mc.w;
      racc[b] += __builtin_fabsf(sp[0]) + __builtin_fabsf(sp[1]) +
                 __builtin_fabsf(sp[2]) + __builtin_fabsf(sp[3]);
      bf16x4 pb;
      pb[0] = (__bf16)sp[0]; pb[1] = (__bf16)sp[1];
      pb[2] = (__bf16)sp[2]; pb[3] = (__bf16)sp[3];
      pfrag[b] = __builtin_bit_cast(s16x4, pb);
    }
    const float4 mf = *(const float4*)(mpt);  // mask, 2 steps ahead

    // PV: O^T[d][r] += V^T[d][t] P^T[t][r]
#pragma unroll
    for (int b = 0; b < NB; ++b)
#pragma unroll
      for (int dcp = 0; dcp < 4; ++dcp) {
        const s16x8 vv = __builtin_bit_cast(s16x8, vf[b][dcp]);
        const s16x4 lo = __builtin_shufflevector(vv, vv, 0, 1, 2, 3);
        const s16x4 hi = __builtin_shufflevector(vv, vv, 4, 5, 6, 7);
        of[b][dcp] = __builtin_amdgcn_mfma_f32_16x16x16bf16_1k(
            lo, pfrag[b], of[b][dcp], 0, 0, 0);
        of[b][dcp + 4] = __builtin_amdgcn_mfma_f32_16x16x16bf16_1k(
            hi, pfrag[b], of[b][dcp + 4], 0, 0, 0);
      }
    // prefetch next-step V frags
    u16x8 vn[NB][4];
#pragma unroll
    for (int b = 0; b < NB; ++b)
#pragma unroll
      for (int c = 0; c < 4; ++c)
        vn[b][c] = *(const u16x8*)(vpb[b] + c * 512);

    // clamped pointer advance (uniform)
    const int adv = (s < STEPS - 2) ? 2048 : 0;
    const int madv = (s < STEPS - 3) ? 16 : 0;
#pragma unroll
    for (int b = 0; b < NB; ++b) { kpb[b] += adv; vpb[b] += adv; }
    mpt += madv;

    // rotate buffers
#pragma unroll
    for (int b = 0; b < NB; ++b)
#pragma unroll
      for (int c = 0; c < 4; ++c) { kf[b][c] = kn[b][c]; vf[b][c] = vn[b][c]; }
    mc = mn; mn = mf;

    // loose lockstep (raw barrier, no waitcnt semantics) -> L1 reuse of the
    // identical K/V frag addresses across the block's 4 waves.
    if ((s & 1) == 1) __builtin_amdgcn_s_barrier();
  }

  // epilogue: reduce racc across the 4 lane-groups, scale, store
#pragma unroll
  for (int b = 0; b < NB; ++b) {
    float rt = racc[b];
    rt += __shfl_xor(rt, 16, 64);
    rt += __shfl_xor(rt, 32, 64);
    const float inv = 1.0f / fmaxf(rt, 1.0f);
    float* op = out + (((size_t)b * NH + h) * NS + r) * ND + g * 4;
#pragma unroll
    for (int dc = 0; dc < 8; ++dc) {
      float4 o4;
      o4.x = of[b][dc][0] * inv;
      o4.y = of[b][dc][1] * inv;
      o4.z = of[b][dc][2] * inv;
      o4.w = of[b][dc][3] * inv;
      *(float4*)(op + dc * 16) = o4;
    }
  }
}

extern "C" void kernel_launch(void* const* d_in, const int* in_sizes, int n_in,
                              void* d_out, int out_size, void* d_ws, size_t ws_size,
                              hipStream_t stream) {
  const float* q = (const float*)d_in[0];
  const float* k = (const float*)d_in[1];
  const float* v = (const float*)d_in[2];
  const float* mask = (const float*)d_in[3];
  float* out = (float*)d_out;

  const size_t n_qkv = (size_t)NB * NH * NS * ND;  // 8388608 elements
  unsigned short* kpk = (unsigned short*)d_ws;     // 16.8 MB packed K frags
  unsigned short* vpk = kpk + n_qkv;               // 16.8 MB packed V frags

  kpack_kernel<<<dim3(STEPS, NB * NH), 64, 0, stream>>>(k, kpk);
  vpack_kernel<<<dim3(STEPS, NB * NH), 64, 0, stream>>>(v, vpk);
  ret_attn_kernel<<<512, 256, 0, stream>>>(q, kpk, mask, vpk, out);
}